// Round 1
// baseline (765.423 us; speedup 1.0000x reference)
//
#include <hip/hip_runtime.h>

// Problem constants (match reference)
#define NB   4096      // batch
#define NT   256       // steps
#define ND   64        // state dim

// ---------------- cross-lane helpers ----------------
// DPP with full masks + bound_ctrl=1 (all lanes written -> fold-eligible)
template <int CTRL>
__device__ __forceinline__ float dppf(float x) {
  return __int_as_float(__builtin_amdgcn_update_dpp(
      0, __float_as_int(x), CTRL, 0xF, 0xF, true));
}

// x + x[lane^16] via VALU v_permlane16_swap_b32 (gfx950). Direction-safe:
// whichever way the HW pairs (vdst odd rows <-> src even rows, or the
// reverse), summing BOTH outputs of swap(x,x) yields x + partner for every
// lane. Fallback: ds_swizzle xor-16 (BitMode offset = xor<<10 | or<<5 | and).
__device__ __forceinline__ float sum_xor16(float x) {
#if __has_builtin(__builtin_amdgcn_permlane16_swap)
  auto r = __builtin_amdgcn_permlane16_swap(__float_as_int(x), __float_as_int(x),
                                            false, false);
  return __int_as_float((int)r[0]) + __int_as_float((int)r[1]);
#else
  return x + __int_as_float(__builtin_amdgcn_ds_swizzle(__float_as_int(x), 0x401F));
#endif
}

// x + x[lane^32] via VALU v_permlane32_swap_b32 (gfx950), same direction-safe
// both-outputs-sum trick. Fallback: ds_bpermute (crosses the 32-lane boundary,
// which ds_swizzle cannot).
__device__ __forceinline__ float sum_xor32(float x, int lane) {
#if __has_builtin(__builtin_amdgcn_permlane32_swap)
  auto r = __builtin_amdgcn_permlane32_swap(__float_as_int(x), __float_as_int(x),
                                            false, false);
  return __int_as_float((int)r[0]) + __int_as_float((int)r[1]);
#else
  return x + __int_as_float(
      __builtin_amdgcn_ds_bpermute((lane ^ 32) << 2, __float_as_int(x)));
#endif
}

// max over 8-lane groups: quad_perm(1,0,3,2), quad_perm(2,3,0,1), row_half_mirror
__device__ __forceinline__ float max8(float x) {
  float t = fmaxf(x, dppf<0xB1>(x));
  t = fmaxf(t, dppf<0x4E>(t));
  t = fmaxf(t, dppf<0x141>(t));
  return t;
}

// 16-term rotation-MAC over a 16-lane DPP row (row_ror:r presents lane
// ((s-r)&15)'s value at lane s), two accumulator chains for ILP.
__device__ __forceinline__ float mac16(float v, const float w[16], float init) {
  float a0 = fmaf(v, w[0], init);
  float a1 = dppf<0x121>(v) * w[1];
  a0 = fmaf(dppf<0x122>(v), w[2], a0);
  a1 = fmaf(dppf<0x123>(v), w[3], a1);
  a0 = fmaf(dppf<0x124>(v), w[4], a0);
  a1 = fmaf(dppf<0x125>(v), w[5], a1);
  a0 = fmaf(dppf<0x126>(v), w[6], a0);
  a1 = fmaf(dppf<0x127>(v), w[7], a1);
  a0 = fmaf(dppf<0x128>(v), w[8], a0);
  a1 = fmaf(dppf<0x129>(v), w[9], a1);
  a0 = fmaf(dppf<0x12A>(v), w[10], a0);
  a1 = fmaf(dppf<0x12B>(v), w[11], a1);
  a0 = fmaf(dppf<0x12C>(v), w[12], a0);
  a1 = fmaf(dppf<0x12D>(v), w[13], a1);
  a0 = fmaf(dppf<0x12E>(v), w[14], a0);
  a1 = fmaf(dppf<0x12F>(v), w[15], a1);
  return a0 + a1;
}

// ===================== Kernel A =====================
// h1pre[b][t][j] = states[b][t][:] . W1[0:64][j] + b1[j]  -> written into `out`.
// 1 row/thread; kc loop NOT unrolled so the ~4.5 KB body stays I$-resident.
__global__ __launch_bounds__(256)
void h1pre_kernel(const float* __restrict__ S,
                  const float* __restrict__ W1,
                  const float* __restrict__ b1,
                  float* __restrict__ out) {
  const size_t row = (size_t)blockIdx.x * 256 + threadIdx.x;   // 0 .. B*T-1
  const float4* srow = (const float4*)(S + row * ND);

  float acc[32];
#pragma unroll
  for (int j = 0; j < 32; ++j) acc[j] = b1[j];                 // uniform -> s_load

#pragma unroll 1
  for (int kc = 0; kc < 4; ++kc) {                             // resident loop body
    float4 x[4];
#pragma unroll
    for (int i = 0; i < 4; ++i) x[i] = srow[kc * 4 + i];
#pragma unroll
    for (int i = 0; i < 4; ++i) {
      const float xv[4] = {x[i].x, x[i].y, x[i].z, x[i].w};
#pragma unroll
      for (int kk = 0; kk < 4; ++kk) {
        const int k = kc * 16 + i * 4 + kk;
#pragma unroll
        for (int j = 0; j < 32; ++j)
          acc[j] = fmaf(xv[kk], W1[k * 32 + j], acc[j]);       // uniform -> s_load
      }
    }
  }

  float4* orow = (float4*)(out + row * 32);
#pragma unroll
  for (int q = 0; q < 8; ++q)
    orow[q] = make_float4(acc[4*q], acc[4*q+1], acc[4*q+2], acc[4*q+3]);
}

// ===================== Kernel B =====================
// Wave = ONE batch. NEW layout (vs previous round): lane = s + 16*g with
//   kh = g&1  (k-half this lane's 16 weights cover)
//   jh = g>>1 (neuron-half), owned neuron j = s + 16*jh
// Row contents are therefore [A0, A1, B0, B1] (X_kh = partials of neuron-half
// X over k-half kh). This makes:
//   combine      = sum with lane^16 partner  -> VALU permlane16_swap pair-sum
//   redistribute = mask rows {0,3} ([A,0,0,B]) then sum with lane^32 partner
//                  -> [A,B,A,B] = h[s+16*kh] at every lane, VALU permlane32_swap
// ALL ds_bpermutes are gone: zero LDS-pipe ops in the recurrence loop, so the
// serial per-step latency is just the fmac chains + a few 1-cycle permlanes.
// Init terms (h1pre, biases, gumbel) enter on kh==0 rows (0,2) exactly once.
__global__ __launch_bounds__(256, 4)
void rec_kernel(const float* __restrict__ G,   // gumbel  [B][T][32]
                const float* __restrict__ W1,  // [96][32] (rows 64..95 used)
                const float* __restrict__ W2,  // [32][32]
                const float* __restrict__ b2,  // [32]
                const float* __restrict__ W3,  // [32][32]
                const float* __restrict__ b3,  // [32]
                float* __restrict__ out) {     // in: h1pre, out: y  [B][T][32]
  const int tid  = threadIdx.x;
  const int wave = tid >> 6;
  const int lane = tid & 63;
  const int s    = lane & 15;
  const int g    = lane >> 4;            // row 0..3
  const int kh   = g & 1;                // k-half
  const int jh   = g >> 1;               // neuron-half
  const int j    = s + 16 * jh;          // owned neuron
  const int b    = blockIdx.x * 4 + wave;
  const bool init_row = (kh == 0);       // rows 0,2: bias/h1pre/gumbel enter here
  const bool keep     = (g == 0) | (g == 3);  // redistribute mask: z = [A,0,0,B]

  // rotation-ordered weights for this lane's (j, k-half)
  float w1[16], w2[16], w3[16];
#pragma unroll
  for (int r = 0; r < 16; ++r) {
    const int k = ((s - r) & 15) + 16 * kh;
    w1[r] = W1[(64 + k) * 32 + j];
    w2[r] = W2[k * 32 + j];
    w3[r] = W3[k * 32 + j];
  }
  const float bias2 = init_row ? b2[j] : 0.f;
  const float bias3 = init_row ? b3[j] : 0.f;

  // carry, kh-aligned: v[lane] = c_{s+16*kh}; c_k = (k%8==0) -> (s%8==0)
  float v = (s % 8 == 0) ? 1.f : 0.f;

  // software pipeline (distance 2): per-lane column j of h1pre/gumbel.
  // rows 1,3 load duplicates of rows 0,2 (same cache lines; values unused).
  const size_t base = ((size_t)b * NT) * 32 + j;
  float hA = out[base], hB = out[base + 32];
  float gA = G[base],   gB = G[base + 32];

  const int sh = lane & 56;
  const int my = lane & 7;

#pragma unroll 1
  for (int t = 0; t < NT; ++t) {
    const int tp = (t + 2 < NT) ? t + 2 : NT - 1;
    const float hC = out[base + (size_t)tp * 32];
    const float gC = G[base + (size_t)tp * 32];

    // L1: q_j = h1pre_j + c . W1[64:96][:,j]
    float p = mac16(v, w1, init_row ? hA : 0.f);
    float q = sum_xor16(p);                       // combine k-halves -> [A,A,B,B]
    v = sum_xor32(keep ? fmaxf(q, 0.f) : 0.f, lane);  // relu+redist -> [A,B,A,B]

    // L2
    p = mac16(v, w2, bias2);
    q = sum_xor16(p);
    v = sum_xor32(keep ? fmaxf(q, 0.f) : 0.f, lane);

    // L3 (+ gumbel; tau=1>0 monotone, softmax skipped)
    p = mac16(v, w3, init_row ? (bias3 + gA) : 0.f);
    q = sum_xor16(p);                             // logits, rows [C,C,D,D]

    // argmax over 8-lane groups; first-max tie-break matches np.argmax
    const float m = max8(q);
    const unsigned long long bl = __ballot(q == m);
    const unsigned gr = (unsigned)(bl >> sh) & 255u;
    const float y = ((__ffs(gr) - 1) == my) ? 1.f : 0.f;

    // rows 0 (j=s) and 2 (j=16+s) cover each neuron exactly once
    if (init_row) out[base + (size_t)t * 32] = y;

    // next-step carry: y is [yA,yA,yB,yB]; mask rows {0,3} + xor32-sum -> [yA,yB,yA,yB]
    v = sum_xor32(keep ? y : 0.f, lane);

    hA = hB; hB = hC; gA = gB; gB = gC;
  }
}

extern "C" void kernel_launch(void* const* d_in, const int* in_sizes, int n_in,
                              void* d_out, int out_size, void* d_ws, size_t ws_size,
                              hipStream_t stream) {
  const float* S  = (const float*)d_in[0];
  const float* G  = (const float*)d_in[1];
  // d_in[2] = tau (==1.0; argmax invariant for any tau>0 -> unused)
  const float* W1 = (const float*)d_in[3];
  const float* b1 = (const float*)d_in[4];
  const float* W2 = (const float*)d_in[5];
  const float* b2 = (const float*)d_in[6];
  const float* W3 = (const float*)d_in[7];
  const float* b3 = (const float*)d_in[8];
  float* out = (float*)d_out;

  // Kernel A: h1pre -> out. 1 row/thread, B*T threads.
  hipLaunchKernelGGL(h1pre_kernel, dim3((NB * NT) / 256), dim3(256), 0, stream,
                     S, W1, b1, out);
  // Kernel B: recurrence, in-place on out. 1 batch/wave -> 1024 blocks,
  // 4096 waves = 4 waves/SIMD.
  hipLaunchKernelGGL(rec_kernel, dim3(NB / 4), dim3(256), 0, stream,
                     G, W1, W2, b2, W3, b3, out);
}

// Round 3
// 737.411 us; speedup vs baseline: 1.0380x; 1.0380x over previous
//
#include <hip/hip_runtime.h>

// Problem constants (match reference)
#define NB   4096      // batch
#define NT   256       // steps
#define ND   64        // state dim

// ---------------- cross-lane helpers ----------------
// DPP with full masks + bound_ctrl=1 (all lanes written -> fold-eligible)
template <int CTRL>
__device__ __forceinline__ float dppf(float x) {
  return __int_as_float(__builtin_amdgcn_update_dpp(
      0, __float_as_int(x), CTRL, 0xF, 0xF, true));
}

// EXACT exchange with lane^16 partner via ds_swizzle BitMode:
// offset = xor<<10 | or<<5 | and = (16<<10)|0x1F = 0x401F. Crossbar op,
// no LDS storage touched; verified instruction class from earlier rounds.
__device__ __forceinline__ float xchg16(float v) {
  return __int_as_float(__builtin_amdgcn_ds_swizzle(__float_as_int(v), 0x401F));
}

// max over 8-lane groups: quad_perm(1,0,3,2), quad_perm(2,3,0,1), row_half_mirror
__device__ __forceinline__ float max8(float x) {
  float t = fmaxf(x, dppf<0xB1>(x));
  t = fmaxf(t, dppf<0x4E>(t));
  t = fmaxf(t, dppf<0x141>(t));
  return t;
}

// Full k=32 dot product for the lane's owned neuron:
//   sum_r v_rot(r)*wo[r]  (own 16-row, DPP row_ror)  +  sum_r vB_rot(r)*wx[r]
// 4 independent 8-deep fmac chains for ILP. vB (the xor-16 partner image of v)
// is only needed by the d-chains, so its swizzle latency hides under c-chains.
__device__ __forceinline__ float mac32(float v, float vB,
                                       const float wo[16], const float wx[16],
                                       float init) {
  float c0 = fmaf(v, wo[0], init);
  float c1 = dppf<0x121>(v) * wo[1];
  float d0 = vB * wx[0];
  float d1 = dppf<0x121>(vB) * wx[1];
  c0 = fmaf(dppf<0x122>(v),  wo[2],  c0);
  c1 = fmaf(dppf<0x123>(v),  wo[3],  c1);
  d0 = fmaf(dppf<0x122>(vB), wx[2],  d0);
  d1 = fmaf(dppf<0x123>(vB), wx[3],  d1);
  c0 = fmaf(dppf<0x124>(v),  wo[4],  c0);
  c1 = fmaf(dppf<0x125>(v),  wo[5],  c1);
  d0 = fmaf(dppf<0x124>(vB), wx[4],  d0);
  d1 = fmaf(dppf<0x125>(vB), wx[5],  d1);
  c0 = fmaf(dppf<0x126>(v),  wo[6],  c0);
  c1 = fmaf(dppf<0x127>(v),  wo[7],  c1);
  d0 = fmaf(dppf<0x126>(vB), wx[6],  d0);
  d1 = fmaf(dppf<0x127>(vB), wx[7],  d1);
  c0 = fmaf(dppf<0x128>(v),  wo[8],  c0);
  c1 = fmaf(dppf<0x129>(v),  wo[9],  c1);
  d0 = fmaf(dppf<0x128>(vB), wx[8],  d0);
  d1 = fmaf(dppf<0x129>(vB), wx[9],  d1);
  c0 = fmaf(dppf<0x12A>(v),  wo[10], c0);
  c1 = fmaf(dppf<0x12B>(v),  wo[11], c1);
  d0 = fmaf(dppf<0x12A>(vB), wx[10], d0);
  d1 = fmaf(dppf<0x12B>(vB), wx[11], d1);
  c0 = fmaf(dppf<0x12C>(v),  wo[12], c0);
  c1 = fmaf(dppf<0x12D>(v),  wo[13], c1);
  d0 = fmaf(dppf<0x12C>(vB), wx[12], d0);
  d1 = fmaf(dppf<0x12D>(vB), wx[13], d1);
  c0 = fmaf(dppf<0x12E>(v),  wo[14], c0);
  c1 = fmaf(dppf<0x12F>(v),  wo[15], c1);
  d0 = fmaf(dppf<0x12E>(vB), wx[14], d0);
  d1 = fmaf(dppf<0x12F>(vB), wx[15], d1);
  return (c0 + c1) + (d0 + d1);
}

// ===================== Kernel A =====================
// h1pre[b][t][j] = states[b][t][:] . W1[0:64][j] + b1[j]  -> written into `out`.
// 1 row/thread; kc loop NOT unrolled so the ~4.5 KB body stays I$-resident.
__global__ __launch_bounds__(256)
void h1pre_kernel(const float* __restrict__ S,
                  const float* __restrict__ W1,
                  const float* __restrict__ b1,
                  float* __restrict__ out) {
  const size_t row = (size_t)blockIdx.x * 256 + threadIdx.x;   // 0 .. B*T-1
  const float4* srow = (const float4*)(S + row * ND);

  float acc[32];
#pragma unroll
  for (int j = 0; j < 32; ++j) acc[j] = b1[j];                 // uniform -> s_load

#pragma unroll 1
  for (int kc = 0; kc < 4; ++kc) {                             // resident loop body
    float4 x[4];
#pragma unroll
    for (int i = 0; i < 4; ++i) x[i] = srow[kc * 4 + i];
#pragma unroll
    for (int i = 0; i < 4; ++i) {
      const float xv[4] = {x[i].x, x[i].y, x[i].z, x[i].w};
#pragma unroll
      for (int kk = 0; kk < 4; ++kk) {
        const int k = kc * 16 + i * 4 + kk;
#pragma unroll
        for (int j = 0; j < 32; ++j)
          acc[j] = fmaf(xv[kk], W1[k * 32 + j], acc[j]);       // uniform -> s_load
      }
    }
  }

  float4* orow = (float4*)(out + row * 32);
#pragma unroll
  for (int q = 0; q < 8; ++q)
    orow[q] = make_float4(acc[4*q], acc[4*q+1], acc[4*q+2], acc[4*q+3]);
}

// ===================== Kernel B =====================
// 2 batches per wave, 32 lanes per batch, lane owns ONE full neuron l = lane&31
// (all 32 k terms). Consequences:
//   - recurrence carry y -> v is LANE-LOCAL (zero cross-lane on serial path)
//   - no combine / no redistribute; per layer 32 fmac_dpp + 1 relu
//   - only cross-lane per layer: one ds_swizzle xor-16 of v at layer START
//     (feeds only the other-row chains; latency hides under own-row fmacs)
//   - h1pre/bias/gumbel inits are lane-local (no masking)
//   - one max8/ballot epilogue serves BOTH batches (64-bit ballot splits)
//   - loads/stores: 64 lanes cover 64 distinct columns, fully coalesced
// 2048 waves -> 2 waves/SIMD (grid-limited). Distance-2 load pipeline (the
// proven round-0/1 rotate pattern) covers HBM latency; out re-reads hit L3.
__global__ __launch_bounds__(256, 2)
void rec_kernel(const float* __restrict__ G,   // gumbel  [B][T][32]
                const float* __restrict__ W1,  // [96][32] (rows 64..95 used)
                const float* __restrict__ W2,  // [32][32]
                const float* __restrict__ b2,  // [32]
                const float* __restrict__ W3,  // [32][32]
                const float* __restrict__ b3,  // [32]
                float* __restrict__ out) {     // in: h1pre, out: y  [B][T][32]
  const int tid  = threadIdx.x;
  const int wave = tid >> 6;
  const int lane = tid & 63;
  const int half = lane >> 5;            // batch-within-wave
  const int l    = lane & 31;            // owned neuron (column)
  const int s    = lane & 15;
  const int rw   = (lane >> 4) & 1;      // own k-row (16-block own-row DPP covers)
  const int b    = (blockIdx.x * 4 + wave) * 2 + half;

  // rotation-ordered weights: own-row block and other-row (xor-16) block
  float w1o[16], w1x[16], w2o[16], w2x[16], w3o[16], w3x[16];
#pragma unroll
  for (int r = 0; r < 16; ++r) {
    const int kO = ((s - r) & 15) + 16 * rw;
    const int kX = ((s - r) & 15) + 16 * (1 - rw);
    w1o[r] = W1[(64 + kO) * 32 + l];
    w1x[r] = W1[(64 + kX) * 32 + l];
    w2o[r] = W2[kO * 32 + l];
    w2x[r] = W2[kX * 32 + l];
    w3o[r] = W3[kO * 32 + l];
    w3x[r] = W3[kX * 32 + l];
  }
  const float b2l = b2[l];
  const float b3l = b3[l];

  // carry: v[lane] = c0[l] = 1 iff l%8==0
  float v = ((l & 7) == 0) ? 1.f : 0.f;

  // distance-2 software pipeline on per-lane column l of h1pre/gumbel
  const size_t base = ((size_t)b * NT) * 32 + l;
  float hA = out[base], hB = out[base + 32];
  float gA = G[base],   gB = G[base + 32];

  const int sh = lane & 56;
  const int my = lane & 7;

#pragma unroll 1
  for (int t = 0; t < NT; ++t) {
    const int tp = (t + 2 < NT) ? t + 2 : NT - 1;
    const float hC = out[base + (size_t)tp * 32];
    const float gC = G[base + (size_t)tp * 32];

    // L1: q_l = h1pre_l + c . W1[64:96][:,l]
    float vB = xchg16(v);
    float p  = mac32(v, vB, w1o, w1x, hA);
    v  = fmaxf(p, 0.f);

    // L2
    vB = xchg16(v);
    p  = mac32(v, vB, w2o, w2x, b2l);
    v  = fmaxf(p, 0.f);

    // L3 (+ gumbel; tau=1>0 monotone, softmax skipped)
    vB = xchg16(v);
    const float q = mac32(v, vB, w3o, w3x, b3l + gA);

    // argmax over 8-lane groups (= cd=8 categories); 64-bit ballot covers
    // both batches; first-max tie-break matches np.argmax
    const float m = max8(q);
    const unsigned long long bl = __ballot(q == m);
    const unsigned gr = (unsigned)(bl >> sh) & 255u;
    const float y = ((__ffs(gr) - 1) == my) ? 1.f : 0.f;

    out[base + (size_t)t * 32] = y;      // all 64 lanes useful, coalesced
    v = y;                               // lane-local carry: no cross-lane!

    hA = hB; hB = hC; gA = gB; gB = gC;
  }
}

extern "C" void kernel_launch(void* const* d_in, const int* in_sizes, int n_in,
                              void* d_out, int out_size, void* d_ws, size_t ws_size,
                              hipStream_t stream) {
  const float* S  = (const float*)d_in[0];
  const float* G  = (const float*)d_in[1];
  // d_in[2] = tau (==1.0; argmax invariant for any tau>0 -> unused)
  const float* W1 = (const float*)d_in[3];
  const float* b1 = (const float*)d_in[4];
  const float* W2 = (const float*)d_in[5];
  const float* b2 = (const float*)d_in[6];
  const float* W3 = (const float*)d_in[7];
  const float* b3 = (const float*)d_in[8];
  float* out = (float*)d_out;

  // Kernel A: h1pre -> out. 1 row/thread, B*T threads.
  hipLaunchKernelGGL(h1pre_kernel, dim3((NB * NT) / 256), dim3(256), 0, stream,
                     S, W1, b1, out);
  // Kernel B: recurrence, in-place on out. 2 batches/wave -> 512 blocks,
  // 2048 waves = 2 waves/SIMD.
  hipLaunchKernelGGL(rec_kernel, dim3(NB / 8), dim3(256), 0, stream,
                     G, W1, W2, b2, W3, b3, out);
}